// Round 1
// baseline (421.679 us; speedup 1.0000x reference)
//
#include <hip/hip_runtime.h>

#define CC 19
#define NPOS 361
#define NPAD 384
#define DIM 256
#define BB 32
#define TKEY 64
#define NTILES 6

// LDS layout (bytes):
//   sQ  : 32 x 264 bf16 = 16896   [0)        reused as attn-out (sAO) in epilogue
//   sK  : 64 x 264 bf16 = 33792   [16896)    reused as proj intermediate
//   sVT : 256 x 72 bf16 = 36864   [50688)
//   sXP : max(sX 64x264=33792, sP 8x32x72=36864) = 36864  [87552)
// total = 124416
#define LDS_BYTES 124416

using bf16x8 = __attribute__((ext_vector_type(8))) short;
using floatx4 = __attribute__((ext_vector_type(4))) float;

__device__ __forceinline__ unsigned short f2bf(float f) {
  unsigned u = __builtin_bit_cast(unsigned, f);
  u += 0x7fffu + ((u >> 16) & 1u);
  return (unsigned short)(u >> 16);
}

__global__ void conv_x_kernel(const float* __restrict__ x, unsigned short* __restrict__ xbf) {
  const int i = blockIdx.x * 256 + threadIdx.x;   // 4 elts per thread
  const int row = i >> 6;                          // padded row 0..12287
  const int off = (i & 63) << 2;
  const int b = row / NPAD;
  const int r = row - b * NPAD;
  float4 v = make_float4(0.f, 0.f, 0.f, 0.f);
  if (r < NPOS) v = *(const float4*)&x[(b * NPOS + r) * DIM + off];
  ushort4 o;
  o.x = f2bf(v.x); o.y = f2bf(v.y); o.z = f2bf(v.z); o.w = f2bf(v.w);
  *(ushort4*)&xbf[row * DIM + off] = o;
}

__global__ void conv_w_kernel(const float* __restrict__ src, unsigned short* __restrict__ dst, int n4) {
  const int i = blockIdx.x * 256 + threadIdx.x;
  if (i >= n4) return;
  const float4 v = *(const float4*)&src[i << 2];
  ushort4 o;
  o.x = f2bf(v.x); o.y = f2bf(v.y); o.z = f2bf(v.z); o.w = f2bf(v.w);
  *(ushort4*)&dst[i << 2] = o;
}

__launch_bounds__(512, 2)
__global__ void cgca_kernel(const float* __restrict__ xf,
                            const float* __restrict__ b_in,
                            const float* __restrict__ b_out,
                            const float* __restrict__ b_fuse,
                            const unsigned short* __restrict__ xbf,
                            const unsigned short* __restrict__ wibf,
                            const unsigned short* __restrict__ wobf,
                            const unsigned short* __restrict__ wfbf,
                            float* __restrict__ out) {
  const int b = blockIdx.x;
  const int c = blockIdx.y;
  const int tid = threadIdx.x;
  const int w = tid >> 6;        // wave 0..7 == head index
  const int lane = tid & 63;
  const int quad = lane >> 4;
  const int l16 = lane & 15;

  extern __shared__ char smem[];
  unsigned short* sQ  = (unsigned short*)(smem);
  unsigned short* sK  = (unsigned short*)(smem + 16896);
  unsigned short* sVT = (unsigned short*)(smem + 50688);
  unsigned short* sX  = (unsigned short*)(smem + 87552);
  unsigned short* sP  = (unsigned short*)(smem + 87552) + w * (32 * 72);

  const float scale = 0.17677669529663687f;  // 1/sqrt(32)
  const floatx4 fzero = {0.f, 0.f, 0.f, 0.f};

  // ---------------- Phase 1: Q = xq @ wq^T + bq (scaled) -> sQ bf16 [32][264]
  {
    const int eh0 = w * 32;
#pragma unroll
    for (int mt = 0; mt < 2; ++mt) {
      const int xrow = b * NPAD + c * CC + mt * 16 + l16;  // <= 384*b+373, zero-padded
      bf16x8 a8[8];
#pragma unroll
      for (int k = 0; k < 8; ++k)
        a8[k] = *(const bf16x8*)&xbf[xrow * DIM + k * 32 + quad * 8];
#pragma unroll
      for (int nt2 = 0; nt2 < 2; ++nt2) {
        const int e0 = eh0 + nt2 * 16;
        floatx4 acc = fzero;
#pragma unroll
        for (int k = 0; k < 8; ++k) {
          bf16x8 b8 = *(const bf16x8*)&wibf[(c * 768 + e0 + l16) * DIM + k * 32 + quad * 8];
          acc = __builtin_amdgcn_mfma_f32_16x16x32_bf16(a8[k], b8, acc, 0, 0, 0);
        }
        const float bias = b_in[c * 768 + e0 + l16];
#pragma unroll
        for (int r = 0; r < 4; ++r)
          sQ[(mt * 16 + quad * 4 + r) * 264 + e0 + l16] = f2bf((acc[r] + bias) * scale);
      }
    }
  }

  // attention running state (per wave-head; rows q = mt*16 + quad*4 + r)
  floatx4 o_acc[2][2];
  float m_run[2][4], l_run[2][4];
#pragma unroll
  for (int mt = 0; mt < 2; ++mt) {
#pragma unroll
    for (int nt2 = 0; nt2 < 2; ++nt2) o_acc[mt][nt2] = fzero;
#pragma unroll
    for (int r = 0; r < 4; ++r) { m_run[mt][r] = -1e30f; l_run[mt][r] = 0.f; }
  }
  const int eh = w * 32;

  for (int t = 0; t < NTILES; ++t) {
    const int t0 = t * TKEY;
    __syncthreads();  // protect sX(=sP) + sK/sVT reuse from previous tile

    // stage x tile [64][264 padded] bf16
#pragma unroll
    for (int it = 0; it < 4; ++it) {
      const int cc2 = tid + it * 512;
      const int row = cc2 >> 5;
      const int col = (cc2 & 31) * 8;
      *(bf16x8*)&sX[row * 264 + col] = *(const bf16x8*)&xbf[(b * NPAD + t0 + row) * DIM + col];
    }
    __syncthreads();

    // ---------------- KV^T projection: rows e' = w*64..w*64+63 of [wk;wv]
    {
      floatx4 acc[4][4];
#pragma unroll
      for (int m4 = 0; m4 < 4; ++m4)
#pragma unroll
        for (int n4 = 0; n4 < 4; ++n4) acc[m4][n4] = fzero;

      const int wrow0 = c * 768 + 256 + w * 64;
      bf16x8 abuf[2][4];
#pragma unroll
      for (int m4 = 0; m4 < 4; ++m4)
        abuf[0][m4] = *(const bf16x8*)&wibf[(wrow0 + m4 * 16 + l16) * DIM + quad * 8];
#pragma unroll
      for (int k = 0; k < 8; ++k) {
        if (k < 7) {
#pragma unroll
          for (int m4 = 0; m4 < 4; ++m4)
            abuf[(k + 1) & 1][m4] =
                *(const bf16x8*)&wibf[(wrow0 + m4 * 16 + l16) * DIM + (k + 1) * 32 + quad * 8];
        }
        bf16x8 bfr[4];
#pragma unroll
        for (int n4 = 0; n4 < 4; ++n4)
          bfr[n4] = *(const bf16x8*)&sX[(n4 * 16 + l16) * 264 + k * 32 + quad * 8];
#pragma unroll
        for (int m4 = 0; m4 < 4; ++m4)
#pragma unroll
          for (int n4 = 0; n4 < 4; ++n4)
            acc[m4][n4] = __builtin_amdgcn_mfma_f32_16x16x32_bf16(abuf[k & 1][m4], bfr[n4],
                                                                  acc[m4][n4], 0, 0, 0);
      }
      // epilogue: +bias, cvt bf16, store K [key][e] / V^T [e][key]
#pragma unroll
      for (int m4 = 0; m4 < 4; ++m4) {
        const float4 bv = *(const float4*)&b_in[c * 768 + 256 + w * 64 + m4 * 16 + quad * 4];
        const float ba[4] = {bv.x, bv.y, bv.z, bv.w};
#pragma unroll
        for (int n4 = 0; n4 < 4; ++n4) {
          const int key = n4 * 16 + l16;
          if (w < 4) {
            const int e0 = w * 64 + m4 * 16 + quad * 4;
            ushort4 pk;
            pk.x = f2bf(acc[m4][n4][0] + ba[0]);
            pk.y = f2bf(acc[m4][n4][1] + ba[1]);
            pk.z = f2bf(acc[m4][n4][2] + ba[2]);
            pk.w = f2bf(acc[m4][n4][3] + ba[3]);
            *(ushort4*)&sK[key * 264 + e0] = pk;
          } else {
            const int e0 = (w - 4) * 64 + m4 * 16 + quad * 4;
#pragma unroll
            for (int r = 0; r < 4; ++r)
              sVT[(e0 + r) * 72 + key] = f2bf(acc[m4][n4][r] + ba[r]);
          }
        }
      }
    }
    __syncthreads();

    // ---------------- scores + mask + online softmax + P (head = w)
    {
#pragma unroll
      for (int mt = 0; mt < 2; ++mt) {
        const bf16x8 aq = *(const bf16x8*)&sQ[(mt * 16 + l16) * 264 + eh + quad * 8];
        floatx4 sc[4];
#pragma unroll
        for (int n4 = 0; n4 < 4; ++n4) {
          const bf16x8 bk = *(const bf16x8*)&sK[(n4 * 16 + l16) * 264 + eh + quad * 8];
          sc[n4] = __builtin_amdgcn_mfma_f32_16x16x32_bf16(aq, bk, fzero, 0, 0, 0);
        }
        float rowm[4] = {-1e30f, -1e30f, -1e30f, -1e30f};
#pragma unroll
        for (int n4 = 0; n4 < 4; ++n4) {
          const int kabs = t0 + n4 * 16 + l16;
          const unsigned ki = ((unsigned)kabs * 110377u) >> 21;  // kabs/19 for kabs<=383
          const unsigned kj = (unsigned)kabs - ki * 19u;
#pragma unroll
          for (int r = 0; r < 4; ++r) {
            const unsigned j = (unsigned)(mt * 16 + quad * 4 + r);
            const bool ok = (kabs < NPOS) &&
                            (ki == (unsigned)c || kj == (unsigned)c || ki == j || kj == j);
            const float v = ok ? sc[n4][r] : -1e30f;
            sc[n4][r] = v;
            rowm[r] = fmaxf(rowm[r], v);
          }
        }
#pragma unroll
        for (int r = 0; r < 4; ++r) {
#pragma unroll
          for (int m = 1; m < 16; m <<= 1) rowm[r] = fmaxf(rowm[r], __shfl_xor(rowm[r], m));
        }
        float alpha[4];
#pragma unroll
        for (int r = 0; r < 4; ++r) {
          const float mnew = fmaxf(m_run[mt][r], rowm[r]);
          alpha[r] = __expf(m_run[mt][r] - mnew);
          m_run[mt][r] = mnew;
          l_run[mt][r] *= alpha[r];
        }
        float rs[4] = {0.f, 0.f, 0.f, 0.f};
#pragma unroll
        for (int n4 = 0; n4 < 4; ++n4) {
#pragma unroll
          for (int r = 0; r < 4; ++r) {
            const float p = __expf(sc[n4][r] - m_run[mt][r]);
            rs[r] += p;
            sP[(mt * 16 + quad * 4 + r) * 72 + n4 * 16 + l16] = f2bf(p);
          }
        }
#pragma unroll
        for (int r = 0; r < 4; ++r) {
#pragma unroll
          for (int m = 1; m < 16; m <<= 1) rs[r] += __shfl_xor(rs[r], m);
          l_run[mt][r] += rs[r];
        }
#pragma unroll
        for (int nt2 = 0; nt2 < 2; ++nt2)
#pragma unroll
          for (int r = 0; r < 4; ++r) o_acc[mt][nt2][r] *= alpha[r];
      }
    }
    __syncthreads();

    // ---------------- PV: O += P @ V (head = w)
#pragma unroll
    for (int ks = 0; ks < 2; ++ks) {
      bf16x8 ap[2], bv8[2];
#pragma unroll
      for (int mt = 0; mt < 2; ++mt)
        ap[mt] = *(const bf16x8*)&sP[(mt * 16 + l16) * 72 + ks * 32 + quad * 8];
#pragma unroll
      for (int nt2 = 0; nt2 < 2; ++nt2)
        bv8[nt2] = *(const bf16x8*)&sVT[(eh + nt2 * 16 + l16) * 72 + ks * 32 + quad * 8];
#pragma unroll
      for (int mt = 0; mt < 2; ++mt)
#pragma unroll
        for (int nt2 = 0; nt2 < 2; ++nt2)
          o_acc[mt][nt2] =
              __builtin_amdgcn_mfma_f32_16x16x32_bf16(ap[mt], bv8[nt2], o_acc[mt][nt2], 0, 0, 0);
    }
  }  // tile loop

  // ---------------- finalize O -> sQ (as attn-out, bf16)
#pragma unroll
  for (int mt = 0; mt < 2; ++mt) {
    float invl[4];
#pragma unroll
    for (int r = 0; r < 4; ++r) invl[r] = 1.f / l_run[mt][r];
#pragma unroll
    for (int nt2 = 0; nt2 < 2; ++nt2)
#pragma unroll
      for (int r = 0; r < 4; ++r)
        sQ[(mt * 16 + quad * 4 + r) * 264 + eh + nt2 * 16 + l16] = f2bf(o_acc[mt][nt2][r] * invl[r]);
  }
  __syncthreads();

  // ---------------- GEMM1: proj = AO @ w_out^T + b_out -> sK (bf16)
#pragma unroll
  for (int mt = 0; mt < 2; ++mt) {
    bf16x8 a8[8];
#pragma unroll
    for (int k = 0; k < 8; ++k)
      a8[k] = *(const bf16x8*)&sQ[(mt * 16 + l16) * 264 + k * 32 + quad * 8];
#pragma unroll
    for (int nt2 = 0; nt2 < 2; ++nt2) {
      const int e0 = w * 32 + nt2 * 16;
      floatx4 acc = fzero;
#pragma unroll
      for (int k = 0; k < 8; ++k) {
        bf16x8 b8 = *(const bf16x8*)&wobf[(c * 256 + e0 + l16) * DIM + k * 32 + quad * 8];
        acc = __builtin_amdgcn_mfma_f32_16x16x32_bf16(a8[k], b8, acc, 0, 0, 0);
      }
      const float bias = b_out[c * 256 + e0 + l16];
#pragma unroll
      for (int r = 0; r < 4; ++r)
        sK[(mt * 16 + quad * 4 + r) * 264 + e0 + l16] = f2bf(acc[r] + bias);
    }
  }
  __syncthreads();

  // ---------------- GEMM2: out = proj @ w_fuse^T + b_fuse + x
#pragma unroll
  for (int mt = 0; mt < 2; ++mt) {
    bf16x8 a8[8];
#pragma unroll
    for (int k = 0; k < 8; ++k)
      a8[k] = *(const bf16x8*)&sK[(mt * 16 + l16) * 264 + k * 32 + quad * 8];
#pragma unroll
    for (int nt2 = 0; nt2 < 2; ++nt2) {
      const int e0 = w * 32 + nt2 * 16;
      floatx4 acc = fzero;
#pragma unroll
      for (int k = 0; k < 8; ++k) {
        bf16x8 b8 = *(const bf16x8*)&wfbf[(e0 + l16) * DIM + k * 32 + quad * 8];
        acc = __builtin_amdgcn_mfma_f32_16x16x32_bf16(a8[k], b8, acc, 0, 0, 0);
      }
      const float bfu = b_fuse[e0 + l16];
#pragma unroll
      for (int r = 0; r < 4; ++r) {
        const int row = mt * 16 + quad * 4 + r;
        if (row < CC) {
          const int gp = (b * NPOS + c * CC + row) * DIM + e0 + l16;
          out[gp] = acc[r] + bfu + xf[gp];
        }
      }
    }
  }
}

extern "C" void kernel_launch(void* const* d_in, const int* in_sizes, int n_in,
                              void* d_out, int out_size, void* d_ws, size_t ws_size,
                              hipStream_t stream) {
  const float* x      = (const float*)d_in[0];
  const float* w_in   = (const float*)d_in[1];
  const float* b_in   = (const float*)d_in[2];
  const float* w_out  = (const float*)d_in[3];
  const float* b_out  = (const float*)d_in[4];
  const float* w_fuse = (const float*)d_in[5];
  const float* b_fuse = (const float*)d_in[6];
  float* out = (float*)d_out;

  if (ws_size < (size_t)16384000) return;  // need 15.6 MB of bf16 scratch

  unsigned short* ws = (unsigned short*)d_ws;
  unsigned short* x_bf  = ws;              // 32*384*256   = 3,145,728
  unsigned short* wi_bf = ws + 3145728;    // 19*768*256   = 3,735,552
  unsigned short* wo_bf = ws + 6881280;    // 19*256*256   = 1,245,184
  unsigned short* wf_bf = ws + 8126464;    // 256*256      = 65,536

  conv_x_kernel<<<3072, 256, 0, stream>>>(x, x_bf);
  conv_w_kernel<<<3648, 256, 0, stream>>>(w_in, wi_bf, 3735552 / 4);
  conv_w_kernel<<<1216, 256, 0, stream>>>(w_out, wo_bf, 1245184 / 4);
  conv_w_kernel<<<64, 256, 0, stream>>>(w_fuse, wf_bf, 65536 / 4);

  (void)hipFuncSetAttribute((const void*)cgca_kernel,
                            hipFuncAttributeMaxDynamicSharedMemorySize, LDS_BYTES);
  cgca_kernel<<<dim3(BB, CC), 512, LDS_BYTES, stream>>>(x, b_in, b_out, b_fuse, x_bf, wi_bf,
                                                        wo_bf, wf_bf, out);
}